// Round 8
// baseline (823.728 us; speedup 1.0000x reference)
//
#include <hip/hip_runtime.h>
#include <hip/hip_bf16.h>
#include <hip/hip_cooperative_groups.h>

// CapsuleLayer dynamic routing. B=64, I=2048, D=16, J=32, K=16, routings=3.
// Round 19: SINGLE cooperative kernel (grid 256x512, 1 block/CU, 5 grid
// syncs) replaces 6 launches. Rationale: r15-r18 = four nulls on schedule
// micro-fixes; totals pinned ~192-195 because the measurement is dominated
// by harness fill (41us, evicts L3 each iteration) + fixed per-launch/
// boundary costs + W re-read 3x. This kernel: W from HBM once (L3 after),
// x/W staged per round, part exchanged fragment-native (no ctile, coalesced
// 256-B stores), vsum in slot layout (coalesced vv loads), only the final
// 128-KB out write is canonical.
// Proven pieces reused verbatim from r18 (absmax 0.0039): 24-short W rows,
// mfma_f32_32x32x16_bf16 operand maps (A row=(jp,k) d-half h; C col=b,
// row=jp*16+(q&3)+8*((q>>2)&1)+4h), ebuf in-block softmax, lgkmcnt-only
// barriers (hipcc drains vmcnt at __syncthreads — r16 lesson), dbuf restage.
// Cross-XCD: __threadfence() (agent scope, flushes XCD L2) before/after
// every grid.sync around part/vsum exchanges (Guideline 16).
// Lessons kept: never force min-waves (r8); coalesced stores only (r13).

#define B_ 64
#define I_ 2048
#define D_ 16
#define J_ 32
#define K_ 16
#define JK 512
#define NBLK 256
#define GI 8
#define NSLOT 32768  // 64 b * 512 jk slots per partial

typedef __attribute__((ext_vector_type(8))) short short8;
typedef __attribute__((ext_vector_type(16))) float float16v;

__device__ __forceinline__ unsigned short f2bf(float f) {
    union { float f; unsigned int i; } v;
    v.f = f;
    const unsigned int x = v.i;
    return (unsigned short)((x + 0x7fffu + ((x >> 16) & 1u)) >> 16);  // RNE
}

// LDS-only barrier: leaves global loads in flight (no vmcnt drain).
__device__ __forceinline__ void bar_lds() {
    asm volatile("s_waitcnt lgkmcnt(0)\n\ts_barrier" ::: "memory");
}

// ---------------------------------------------------------------------------
// Fused 3-round routing. Wave w: bt=w&1 (b-tile of 32), jg=w>>1 (j-octet).
// Lane: b = bt*32+(lane&31), h = lane>>5 (d-half of frags / k-half of C).
// Slot layout (part, vsum): s = ((w*4+m)*16 + jp*8 + q)*64 + h*32 + l31
//   <-> (b = (w&1)*32+l31, j = (w>>1)*8+m*2+jp, k = (q&3)+8*((q>>2)&1)+4h).
// Reduction: block bk owns 8 (b,j)-groups: rw=bk>>5, rm=(bk>>3)&3,
// rjp=(bk>>2)&1, L0=(bk&3)*8; thread idx=(rq,rh,dl), 4-way p-split via pq.
// ---------------------------------------------------------------------------
__global__ __launch_bounds__(512)
void caps_fused(const float* __restrict__ x, const float* __restrict__ W,
                float* __restrict__ part, float* __restrict__ vsum,
                float* __restrict__ out) {
    cooperative_groups::grid_group grid = cooperative_groups::this_grid();
    __shared__ unsigned short wlds[2][12288];  // 2 x 24 KB (512 rows x 24 sh)
    __shared__ float ebuf[2][2][4][32];        // [t-par][bt][jg][l31]
    __shared__ float red[4][128];

    const int tid = threadIdx.x;
    const int lane = tid & 63;
    const int w = tid >> 6;
    const int bt = w & 1, jg = w >> 1;
    const int l31 = lane & 31, h = lane >> 5;
    const int b = bt * 32 + l31;
    const int bk = blockIdx.x;
    const int i0 = bk * GI;

    // staging thread column: row = tid (j = tid>>4, k = tid&15)
    const float* wp =
        W + (size_t)i0 * (J_ * D_ * K_) + (tid >> 4) * (D_ * K_) + (tid & 15);
    const float* xb = x + (size_t)b * I_ * D_ + h * 8;
    const int abase = ((jg * 8 + (l31 >> 4)) * 16 + (l31 & 15)) * 24 + h * 8;

    // reduction-phase constants
    const int rw = bk >> 5, rm = (bk >> 3) & 3, rjp = (bk >> 2) & 1;
    const int L0 = (bk & 3) * 8;
    const int idx = tid & 127, pq = tid >> 7;
    const int rq = idx >> 4, rh = (idx >> 3) & 1, dl = idx & 7;
    const int rslot = ((rw * 4 + rm) * 16 + rjp * 8 + rq) * 64 + rh * 32 +
                      L0 + dl;

    for (int rnd = 0; rnd < 3; ++rnd) {
        // ---- vv: coalesced slot-layout loads (rounds 1,2) ----
        float vv[4][2][8];
        if (rnd > 0) {
#pragma unroll
            for (int m = 0; m < 4; ++m)
#pragma unroll
                for (int jp = 0; jp < 2; ++jp)
#pragma unroll
                    for (int q = 0; q < 8; ++q)
                        vv[m][jp][q] =
                            vsum[(size_t)((w * 4 + m) * 16 + jp * 8 + q) * 64 +
                                 lane];
        }

        float16v acc[4];
#pragma unroll
        for (int m = 0; m < 4; ++m)
#pragma unroll
            for (int r = 0; r < 16; ++r) acc[m][r] = 0.f;

        // ---- prologue: stage W[i0] -> wlds[0] ----
        {
            float vals[16];
#pragma unroll
            for (int d = 0; d < 16; ++d) vals[d] = wp[d * K_];
            unsigned int pk[8];
#pragma unroll
            for (int q = 0; q < 8; ++q)
                pk[q] = ((unsigned int)f2bf(vals[2 * q + 1]) << 16) |
                        f2bf(vals[2 * q]);
            uint4* dst = reinterpret_cast<uint4*>(&wlds[0][tid * 24]);
            uint4 w0; w0.x = pk[0]; w0.y = pk[1]; w0.z = pk[2]; w0.w = pk[3];
            uint4 w1; w1.x = pk[4]; w1.y = pk[5]; w1.z = pk[6]; w1.w = pk[7];
            dst[0] = w0; dst[1] = w1;
        }

        for (int t = 0; t < GI; ++t) {
            const int p = t & 1;
            bar_lds();  // B1: wlds[p] ready (stores from prev iter / prologue)

            // prefetch W[i+1] (crosses B2 in flight; lgkmcnt-only barriers)
            float nv[16];
            if (t < GI - 1) {
                const float* wn = wp + (size_t)(t + 1) * (J_ * D_ * K_);
#pragma unroll
                for (int d = 0; d < 16; ++d) nv[d] = wn[d * K_];
            }

            // x B-frag: x[b][i0+t][8h..8h+7] packed bf16
            union { uint4 u; short8 s; } bfrag;
            {
                const float* xp = xb + (size_t)(i0 + t) * D_;
                const float4 x0 = reinterpret_cast<const float4*>(xp)[0];
                const float4 x1 = reinterpret_cast<const float4*>(xp)[1];
                bfrag.u.x = ((unsigned int)f2bf(x0.y) << 16) | f2bf(x0.x);
                bfrag.u.y = ((unsigned int)f2bf(x0.w) << 16) | f2bf(x0.z);
                bfrag.u.z = ((unsigned int)f2bf(x1.y) << 16) | f2bf(x1.x);
                bfrag.u.w = ((unsigned int)f2bf(x1.w) << 16) | f2bf(x1.z);
            }

            // u_hat: 4 MFMAs 32x32x16, K = d = 16 exact
            float16v u[4];
#pragma unroll
            for (int m = 0; m < 4; ++m) {
                union { uint4 q; short8 s; } af;
                af.q = *reinterpret_cast<const uint4*>(
                    &wlds[p][abase + m * 768]);
                float16v z;
#pragma unroll
                for (int r = 0; r < 16; ++r) z[r] = 0.f;
                u[m] = __builtin_amdgcn_mfma_f32_32x32x16_bf16(af.s, bfrag.s,
                                                               z, 0, 0, 0);
            }

            if (rnd == 0) {
#pragma unroll
                for (int m = 0; m < 4; ++m) acc[m] += u[m];
            } else {
                float e[4][2];
                float E = 0.f;
#pragma unroll
                for (int m = 0; m < 4; ++m)
#pragma unroll
                    for (int jp = 0; jp < 2; ++jp) {
                        const int rb = jp * 8;
                        float pj = u[m][rb + 0] * vv[m][jp][0] +
                                   u[m][rb + 1] * vv[m][jp][1] +
                                   u[m][rb + 2] * vv[m][jp][2] +
                                   u[m][rb + 3] * vv[m][jp][3] +
                                   u[m][rb + 4] * vv[m][jp][4] +
                                   u[m][rb + 5] * vv[m][jp][5] +
                                   u[m][rb + 6] * vv[m][jp][6] +
                                   u[m][rb + 7] * vv[m][jp][7];
                        pj += __shfl_xor(pj, 32, 64);  // merge k-halves
                        const float ee = __expf(pj);
                        e[m][jp] = ee;
                        E += ee;
                    }
                if (h == 0) ebuf[p][bt][jg][l31] = E;
                bar_lds();  // B2: ebuf exchange
                const float Et = ebuf[p][bt][0][l31] + ebuf[p][bt][1][l31] +
                                 ebuf[p][bt][2][l31] + ebuf[p][bt][3][l31];
                const float rr = __builtin_amdgcn_rcpf(Et);
#pragma unroll
                for (int m = 0; m < 4; ++m)
#pragma unroll
                    for (int jp = 0; jp < 2; ++jp) {
                        const float c = e[m][jp] * rr;
#pragma unroll
                        for (int q = 0; q < 8; ++q)
                            acc[m][jp * 8 + q] += c * u[m][jp * 8 + q];
                    }
            }

            // restage prefetch into the other buffer (reads of it ended
            // before B1_t; next reads after B1_{t+1})
            if (t < GI - 1) {
                unsigned int pk[8];
#pragma unroll
                for (int q = 0; q < 8; ++q)
                    pk[q] = ((unsigned int)f2bf(nv[2 * q + 1]) << 16) |
                            f2bf(nv[2 * q]);
                uint4* dst =
                    reinterpret_cast<uint4*>(&wlds[p ^ 1][tid * 24]);
                uint4 w0; w0.x = pk[0]; w0.y = pk[1]; w0.z = pk[2]; w0.w = pk[3];
                uint4 w1; w1.x = pk[4]; w1.y = pk[5]; w1.z = pk[6]; w1.w = pk[7];
                dst[0] = w0; dst[1] = w1;
            }
        }

        // ---- store partial, fragment-native (256-B wave-contiguous) ----
#pragma unroll
        for (int m = 0; m < 4; ++m)
#pragma unroll
            for (int r = 0; r < 16; ++r)
                part[(size_t)bk * NSLOT + ((w * 4 + m) * 16 + r) * 64 + lane] =
                    acc[m][r];

        __threadfence();  // agent scope: flush XCD L2 before cross-block read
        grid.sync();

        // ---- reduction + squash (all 256 blocks) ----
        {
            float s = 0.f;
#pragma unroll 8
            for (int p2 = pq * 64; p2 < pq * 64 + 64; ++p2)
                s += part[(size_t)p2 * NSLOT + rslot];
            if (pq) red[pq - 1][idx] = s;
            __syncthreads();
            if (pq == 0) {
                s += red[0][idx] + red[1][idx] + red[2][idx];
                if (rnd == 0) s *= (1.f / 32.f);
                red[3][idx] = s;
            }
            __syncthreads();
            if (pq == 0 && idx < 8) {
                float nn = 0.f;
#pragma unroll
                for (int q2 = 0; q2 < 16; ++q2) {
                    const float v2 = red[3][(q2 & 7) * 16 + (q2 >> 3) * 8 + idx];
                    nn += v2 * v2;
                }
                red[0][idx] = nn / ((1.f + nn) * sqrtf(nn + 1e-7f));
            }
            __syncthreads();
            if (pq == 0) {
                const float v = red[3][idx] * red[0][dl];
                if (rnd == 0) {
                    vsum[rslot] = v;
                } else if (rnd == 1) {
                    vsum[rslot] += v;  // same thread wrote rnd-0 value
                } else {
                    const int bo = (rw & 1) * 32 + L0 + dl;
                    const int jo = (rw >> 1) * 8 + rm * 2 + rjp;
                    const int ko = (rq & 3) + 8 * ((rq >> 2) & 1) + 4 * rh;
                    out[(size_t)bo * JK + jo * 16 + ko] = v;
                }
            }
            if (rnd < 2) {
                __threadfence();
                grid.sync();
            }
        }
    }
}

// ---------------------------------------------------------------------------
extern "C" void kernel_launch(void* const* d_in, const int* in_sizes, int n_in,
                              void* d_out, int out_size, void* d_ws,
                              size_t ws_size, hipStream_t stream) {
    const float* x = (const float*)d_in[0];  // [B,I,D] f32
    const float* W = (const float*)d_in[1];  // [I,J,D,K] f32
    float* out = (float*)d_out;              // [B,J,K] f32

    char* ws = (char*)d_ws;
    float* part = (float*)ws;                           // 32 MB
    float* vsum = (float*)(ws + (size_t)NBLK * NSLOT * 4);  // 128 KB

    void* args[] = {(void*)&x, (void*)&W, (void*)&part, (void*)&vsum,
                    (void*)&out};
    hipLaunchCooperativeKernel((void*)caps_fused, dim3(NBLK), dim3(512), args,
                               0, stream);
}

// Round 10
// 280.093 us; speedup vs baseline: 2.9409x; 2.9409x over previous
//
#include <hip/hip_runtime.h>
#include <hip/hip_bf16.h>

// CapsuleLayer dynamic routing. B=64, I=2048, D=16, J=32, K=16, routings=3.
// Structure: uhat never hits HBM; pass rnd recomputes u_hat (MFMA 32x32x16,
// K=d=16 exact) and uses b_t = u_hat . vsum linearity. 3 passes + 3 squash.
// History: r15-r18 pass-schedule fixes all NULL at ~191-196 total; r19
// cooperative fusion = 823us disaster (grid.sync L2-invalidate re-fetches W
// 3x; 128KB-stride single-float reduction gather; ~O(100us) syncs). r20:
// compile error (pointer-arith precedence: ws + N<<20), theory untested.
// Round 21 = round 20 with the vsum offset parenthesized correctly.
// Theory: passes were BARRIER-CONVOY bound — every variant ran 1 block/CU
// (512thr x ~200 VGPR), so all 8 waves shared each barrier and nothing was
// resident to absorb stalls. Fix = co-residency, not schedule:
//  - pass: 256-thr blocks (4 waves = 4 j-octets, one 32-b tile), grid
//    256 ichunks x 2 b-halves = 512 blocks = 2 independent barrier domains
//    per CU. Single-buffer wlds (24KB), stage->bar->compute->bar.
//  - part layout [p][s][b] (s=j*16+k): fragment stores are 2x128-B wave
//    segments — no ctile, no epilogue barriers (r13 lesson respected on
//    writes; r16-style coalesced p-walk respected on reads).
//  - vsum in [s][b] slot layout -> coalesced vv loads; squash grid 256
//    (j x b-oct) with in-block k-norm; only final out write is canonical.
// Proven pieces kept verbatim: 24-short W rows, 32x32x16 operand/C maps
// (absmax 0.0039 since r15), lgkmcnt-only barriers (r16 lesson), ebuf
// parity softmax exchange, r16 squash reduction shape. Never force
// min-waves (r8).

#define B_ 64
#define I_ 2048
#define D_ 16
#define J_ 32
#define K_ 16
#define JK 512
#define NIC 256   // i-chunks
#define GI 8      // i's per chunk
#define JDK (J_ * D_ * K_)

typedef __attribute__((ext_vector_type(8))) short short8;
typedef __attribute__((ext_vector_type(16))) float float16v;

__device__ __forceinline__ unsigned short f2bf(float f) {
    union { float f; unsigned int i; } v;
    v.f = f;
    const unsigned int x = v.i;
    return (unsigned short)((x + 0x7fffu + ((x >> 16) & 1u)) >> 16);  // RNE
}

// LDS-only barrier: no vmcnt drain (hipcc's __syncthreads would add one).
__device__ __forceinline__ void bar_lds() {
    asm volatile("s_waitcnt lgkmcnt(0)\n\ts_barrier" ::: "memory");
}

// ---------------------------------------------------------------------------
// Routing pass. MODE 0: acc += u_hat (uniform c; 1/32 applied in squash).
// MODE 1: acc += softmax_j(u_hat . vsum) * u_hat.
// Grid (NIC*2) x 256: ic = blockIdx>>1, bh = blockIdx&1. Wave w = jg (0..3).
// Lane: b = bh*32 + l31; h = lane>>5 = d-half (frags) / k-half (C rows).
// MFMA m: A rows = (j = jg*8+m*2+jp, k), j-pair jp = l31>>4, k = l31&15;
// C: col = b (l31), reg r: jp = r>>3, k = (r&3)+8*((r>>2)&1)+4h.
// ---------------------------------------------------------------------------
template <int MODE>
__global__ __launch_bounds__(256)
void caps_pass(const float* __restrict__ x, const float* __restrict__ W,
               const float* __restrict__ vsum, float* __restrict__ part) {
    __shared__ unsigned short wlds[12288];  // 24 KB: 512 rows (j*16+k) x 24
    __shared__ float ebuf[2][4][32];        // [t-parity][jg][l31]

    const int tid = threadIdx.x;
    const int lane = tid & 63;
    const int jg = tid >> 6;  // wave = j-octet
    const int l31 = lane & 31, h = lane >> 5;
    const int bh = blockIdx.x & 1;
    const int ic = blockIdx.x >> 1;
    const int b = bh * 32 + l31;
    const int i0 = ic * GI;

    // vv[m][jp][q] = vsum_slot[s = (jg*8+m*2+jp)*16 + kq][b],
    // kq = (q&3)+8*((q>>2)&1)+4h  (matches u-reg k map). Coalesced over l31.
    float vv[4][2][8];
    if (MODE == 1) {
#pragma unroll
        for (int m = 0; m < 4; ++m)
#pragma unroll
            for (int jp = 0; jp < 2; ++jp)
#pragma unroll
                for (int q = 0; q < 8; ++q) {
                    const int kq = (q & 3) + 8 * ((q >> 2) & 1) + 4 * h;
                    const int s = (jg * 8 + m * 2 + jp) * 16 + kq;
                    vv[m][jp][q] = vsum[(size_t)s * 64 + b];
                }
    }

    float16v acc[4];
#pragma unroll
    for (int m = 0; m < 4; ++m)
#pragma unroll
        for (int r = 0; r < 16; ++r) acc[m][r] = 0.f;

    // staging: thread covers rows tid and tid+256 (j = tid>>4 and +16)
    const float* wp = W + (size_t)i0 * JDK + (tid >> 4) * (D_ * K_) + (tid & 15);
    const float* xb = x + (size_t)b * I_ * D_ + h * 8;
    const int abase = ((jg * 8 + (l31 >> 4)) * 16 + (l31 & 15)) * 24 + h * 8;

    for (int t = 0; t < GI; ++t) {
        // ---- stage W[i0+t] (prev iter's wlds reads ended before its B2) --
#pragma unroll
        for (int jj = 0; jj < 2; ++jj) {
            const float* p = wp + (size_t)t * JDK + jj * (16 * D_ * K_);
            float vals[16];
#pragma unroll
            for (int d = 0; d < 16; ++d) vals[d] = p[d * K_];
            unsigned int pk[8];
#pragma unroll
            for (int q = 0; q < 8; ++q)
                pk[q] = ((unsigned int)f2bf(vals[2 * q + 1]) << 16) |
                        f2bf(vals[2 * q]);
            uint4* dst =
                reinterpret_cast<uint4*>(&wlds[(tid + jj * 256) * 24]);
            uint4 w0; w0.x = pk[0]; w0.y = pk[1]; w0.z = pk[2]; w0.w = pk[3];
            uint4 w1; w1.x = pk[4]; w1.y = pk[5]; w1.z = pk[6]; w1.w = pk[7];
            dst[0] = w0; dst[1] = w1;
        }
        bar_lds();  // B1: wlds ready

        // x B-frag: x[b][i0+t][8h..8h+7] packed bf16
        union { uint4 u; short8 s; } bfrag;
        {
            const float* xp = xb + (size_t)(i0 + t) * D_;
            const float4 x0 = reinterpret_cast<const float4*>(xp)[0];
            const float4 x1 = reinterpret_cast<const float4*>(xp)[1];
            bfrag.u.x = ((unsigned int)f2bf(x0.y) << 16) | f2bf(x0.x);
            bfrag.u.y = ((unsigned int)f2bf(x0.w) << 16) | f2bf(x0.z);
            bfrag.u.z = ((unsigned int)f2bf(x1.y) << 16) | f2bf(x1.x);
            bfrag.u.w = ((unsigned int)f2bf(x1.w) << 16) | f2bf(x1.z);
        }

        // u_hat: 4 MFMAs, K = d = 16 exact
        float16v u[4];
#pragma unroll
        for (int m = 0; m < 4; ++m) {
            union { uint4 q; short8 s; } af;
            af.q = *reinterpret_cast<const uint4*>(&wlds[abase + m * 768]);
            float16v z;
#pragma unroll
            for (int r = 0; r < 16; ++r) z[r] = 0.f;
            u[m] = __builtin_amdgcn_mfma_f32_32x32x16_bf16(af.s, bfrag.s, z,
                                                           0, 0, 0);
        }

        if (MODE == 0) {
#pragma unroll
            for (int m = 0; m < 4; ++m) acc[m] += u[m];
            bar_lds();  // B2: wlds reads done -> next stage safe
        } else {
            float e[4][2];
            float E = 0.f;
#pragma unroll
            for (int m = 0; m < 4; ++m)
#pragma unroll
                for (int jp = 0; jp < 2; ++jp) {
                    const int rb = jp * 8;
                    float pj = u[m][rb + 0] * vv[m][jp][0] +
                               u[m][rb + 1] * vv[m][jp][1] +
                               u[m][rb + 2] * vv[m][jp][2] +
                               u[m][rb + 3] * vv[m][jp][3] +
                               u[m][rb + 4] * vv[m][jp][4] +
                               u[m][rb + 5] * vv[m][jp][5] +
                               u[m][rb + 6] * vv[m][jp][6] +
                               u[m][rb + 7] * vv[m][jp][7];
                    pj += __shfl_xor(pj, 32, 64);  // merge k-halves
                    const float ee = __expf(pj);   // |p| bounded; f32-safe
                    e[m][jp] = ee;
                    E += ee;
                }
            if (h == 0) ebuf[t & 1][jg][l31] = E;
            bar_lds();  // B2: ebuf visible; wlds reads done (MFMAs above)
            const float Et = ebuf[t & 1][0][l31] + ebuf[t & 1][1][l31] +
                             ebuf[t & 1][2][l31] + ebuf[t & 1][3][l31];
            const float rr = __builtin_amdgcn_rcpf(Et);
#pragma unroll
            for (int m = 0; m < 4; ++m)
#pragma unroll
                for (int jp = 0; jp < 2; ++jp) {
                    const float c = e[m][jp] * rr;
#pragma unroll
                    for (int q = 0; q < 8; ++q)
                        acc[m][jp * 8 + q] += c * u[m][jp * 8 + q];
                }
        }
    }

    // ---- store partial: part[p=ic][s][b] — per (m,r) the wave writes two
    //      128-B b-contiguous segments (h splits k). No ctile needed. ----
#pragma unroll
    for (int m = 0; m < 4; ++m)
#pragma unroll
        for (int r = 0; r < 16; ++r) {
            const int k = (r & 3) + 8 * ((r >> 2) & 1) + 4 * h;
            const int s = (jg * 8 + m * 2 + (r >> 3)) * 16 + k;
            part[((size_t)ic * JK + s) * 64 + b] = acc[m][r];
        }
}

// ---------------------------------------------------------------------------
// Reduce NIC partials + squash. Grid 256 = j(32) x b-oct(8); 512 thr =
// pq(4-way p-split) x idx(128 = k(16) x bo(8)). In-block k-norm.
// MODE 0: vsum = squash(s/32). MODE 1: vsum += squash(s). MODE 2: out.
// ---------------------------------------------------------------------------
template <int MODE>
__global__ __launch_bounds__(512)
void caps_squashN(const float* __restrict__ part, float* __restrict__ vsum,
                  float* __restrict__ out) {
    __shared__ float red[3][128];
    __shared__ float sq[128];
    __shared__ float sc[8];
    const int j = blockIdx.x >> 3;
    const int oct = blockIdx.x & 7;
    const int idx = threadIdx.x & 127;
    const int pq = threadIdx.x >> 7;
    const int k = idx >> 3, bo = idx & 7;
    const int b = oct * 8 + bo;
    const int s = j * 16 + k;

    float t = 0.f;
#pragma unroll 8
    for (int p = pq * (NIC / 4); p < (pq + 1) * (NIC / 4); ++p)
        t += part[((size_t)p * JK + s) * 64 + b];

    if (pq) red[pq - 1][idx] = t;
    __syncthreads();
    if (pq == 0) {
        t += red[0][idx] + red[1][idx] + red[2][idx];
        if (MODE == 0) t *= (1.f / 32.f);
        sq[idx] = t;
    }
    __syncthreads();
    if (pq == 0 && idx < 8) {
        float nn = 0.f;
#pragma unroll
        for (int kk = 0; kk < 16; ++kk) {
            const float v2 = sq[kk * 8 + idx];
            nn += v2 * v2;
        }
        sc[idx] = nn / ((1.f + nn) * sqrtf(nn + 1e-7f));
    }
    __syncthreads();
    if (pq == 0) {
        const float v = sq[idx] * sc[bo];
        if (MODE == 0)      vsum[(size_t)s * 64 + b] = v;
        else if (MODE == 1) vsum[(size_t)s * 64 + b] += v;
        else                out[(size_t)b * JK + j * 16 + k] = v;
    }
}

// ---------------------------------------------------------------------------
extern "C" void kernel_launch(void* const* d_in, const int* in_sizes, int n_in,
                              void* d_out, int out_size, void* d_ws,
                              size_t ws_size, hipStream_t stream) {
    const float* x = (const float*)d_in[0];  // [B,I,D] f32
    const float* W = (const float*)d_in[1];  // [I,J,D,K] f32
    float* out = (float*)d_out;              // [B,J,K] f32

    char* ws = (char*)d_ws;
    float* part = (float*)ws;                             // [NIC][512][64] 33.5 MB
    float* vsum = (float*)(ws + (size_t)(36 << 20));      // [512][64] 128 KB

    // round 0: uniform c = 1/32
    caps_pass<0><<<NIC * 2, 256, 0, stream>>>(x, W, nullptr, part);
    caps_squashN<0><<<256, 512, 0, stream>>>(part, vsum, nullptr);
    // round 1
    caps_pass<1><<<NIC * 2, 256, 0, stream>>>(x, W, vsum, part);
    caps_squashN<1><<<256, 512, 0, stream>>>(part, vsum, nullptr);
    // round 2
    caps_pass<1><<<NIC * 2, 256, 0, stream>>>(x, W, vsum, part);
    caps_squashN<2><<<256, 512, 0, stream>>>(part, vsum, out);
}